// Round 1
// 749.619 us; speedup vs baseline: 1.0428x; 1.0428x over previous
//
#include <hip/hip_runtime.h>

#define BB 8
#define SS 2048
#define HH 3584
#define EE 8
#define RR 16
#define KK 2
#define KR 32          // K*R combined axis, kr = k*16 + r
#define SCALE 2.0f     // lora_alpha / lora_r

// ---------------------------------------------------------------------------
// Scratch layout inside d_out (safe: phase-2 fully overwrites d_out at the
// end and reads none of this):
//   a2t : [BB][HH][KR] floats              (3.67 MB)   routed+transposed A
//   part: [4][BB][SS][KR] floats           (8.39 MB)   per-h-quarter partials
// d_ws keeps low[BB][SS][KR] (2 MB) so phase 2 can read it while writing out.
// ---------------------------------------------------------------------------
#define A2T_FLOATS  (BB * HH * KR)                 // 917,504
#define PART_STRIDE ((size_t)BB * SS * KR)         // 524,288 floats / quarter

// ---------------------------------------------------------------------------
// Prep: A2t[b][h][kr] = lora_A[e(b, kr>>4)][kr&15][h]
// Coalesced reads (consecutive threads = consecutive h), one-time 3.67 MB.
// ---------------------------------------------------------------------------
__global__ __launch_bounds__(256) void prep_kernel(
    const float* __restrict__ lora_A, const int* __restrict__ topk_idx,
    float* __restrict__ a2t)
{
    const int idx = blockIdx.x * 256 + threadIdx.x;   // 0 .. BB*HH-1
    const int b   = idx / HH;
    const int h   = idx - b * HH;
    const int e0  = topk_idx[b * KK + 0];
    const int e1  = topk_idx[b * KK + 1];
    float* dst = a2t + (size_t)idx * KR;
    #pragma unroll
    for (int r = 0; r < RR; ++r) {
        dst[r]      = lora_A[((size_t)e0 * RR + r) * HH + h];
        dst[RR + r] = lora_A[((size_t)e1 * RR + r) * HH + h];
    }
}

// ---------------------------------------------------------------------------
// Phase 1 (rowwise streaming): thread = one s-row; wave w of 4 covers h
// subchunk [hq*896 + w*224, +224). acc[32] in registers. A2t reads are
// wave-uniform (broadcast, L2-resident); x reads are per-lane float4 streams.
// No barriers in the main loop. One-time LDS cross-wave reduce at the end,
// then plain float4 stores of the h-quarter partial (no atomics).
// grid (4, 32, 8) = 1024 blocks x 256 threads; LDS 36.9 KB -> 4 blocks/CU.
// ---------------------------------------------------------------------------
__global__ __launch_bounds__(256) void lora_low_kernel(
    const float* __restrict__ x, const float* __restrict__ a2t,
    float* __restrict__ part)
{
    __shared__ float red[4][64][KR + 4];   // stride 36: float4-aligned, low conflict

    const int tid = threadIdx.x;
    const int w   = tid >> 6;              // wave 0..3 -> h subchunk
    const int l   = tid & 63;              // lane -> row within s-chunk
    const int b   = blockIdx.z;
    const int row = blockIdx.y * 64 + l;
    const int hq  = blockIdx.x;            // h quarter 0..3
    const int h0  = hq * (HH / 4) + w * (HH / 16);   // 896*hq + 224*w

    const float* xp = x + ((size_t)(b * SS + row)) * HH + h0;
    const float* ap = a2t + ((size_t)b * HH + h0) * KR;

    float acc[KR];
    #pragma unroll
    for (int i = 0; i < KR; ++i) acc[i] = 0.0f;

    for (int t = 0; t < (HH / 16) / 4; ++t) {        // 56 float4 steps
        const float4 xv = *reinterpret_cast<const float4*>(xp + t * 4);
        const float xs[4] = {xv.x, xv.y, xv.z, xv.w};
        const float* a = ap + (size_t)t * 4 * KR;    // 4 h-rows x 32 kr, 512 B
        #pragma unroll
        for (int j = 0; j < 4; ++j) {
            #pragma unroll
            for (int q = 0; q < 8; ++q) {
                const float4 av = *reinterpret_cast<const float4*>(a + j * KR + q * 4);
                acc[q * 4 + 0] = fmaf(xs[j], av.x, acc[q * 4 + 0]);
                acc[q * 4 + 1] = fmaf(xs[j], av.y, acc[q * 4 + 1]);
                acc[q * 4 + 2] = fmaf(xs[j], av.z, acc[q * 4 + 2]);
                acc[q * 4 + 3] = fmaf(xs[j], av.w, acc[q * 4 + 3]);
            }
        }
    }

    // ---- one-time cross-wave reduce (4 h-subchunks -> block partial) ----
    #pragma unroll
    for (int q = 0; q < 8; ++q)
        *reinterpret_cast<float4*>(&red[w][l][q * 4]) =
            make_float4(acc[q * 4], acc[q * 4 + 1], acc[q * 4 + 2], acc[q * 4 + 3]);
    __syncthreads();

    // wave w sums kr slice [w*8, w*8+8) across the 4 partial sets
    float o[8];
    #pragma unroll
    for (int j = 0; j < 8; ++j) o[j] = 0.0f;
    #pragma unroll
    for (int wp = 0; wp < 4; ++wp) {
        const float4 u0 = *reinterpret_cast<const float4*>(&red[wp][l][w * 8]);
        const float4 u1 = *reinterpret_cast<const float4*>(&red[wp][l][w * 8 + 4]);
        o[0] += u0.x; o[1] += u0.y; o[2] += u0.z; o[3] += u0.w;
        o[4] += u1.x; o[5] += u1.y; o[6] += u1.z; o[7] += u1.w;
    }
    float* pp = part + (size_t)hq * PART_STRIDE
                     + ((size_t)(b * SS + row)) * KR + w * 8;
    *reinterpret_cast<float4*>(pp)     = make_float4(o[0], o[1], o[2], o[3]);
    *reinterpret_cast<float4*>(pp + 4) = make_float4(o[4], o[5], o[6], o[7]);
}

// ---------------------------------------------------------------------------
// Reduce: low = sum of 4 h-quarter partials. 10 MB traffic, ~3 us.
// ---------------------------------------------------------------------------
__global__ __launch_bounds__(256) void reduce_kernel(
    const float* __restrict__ part, float* __restrict__ low)
{
    const size_t i = ((size_t)blockIdx.x * 256 + threadIdx.x) * 4;
    const float4 a = *reinterpret_cast<const float4*>(part + i);
    const float4 b = *reinterpret_cast<const float4*>(part + PART_STRIDE + i);
    const float4 c = *reinterpret_cast<const float4*>(part + 2 * PART_STRIDE + i);
    const float4 d = *reinterpret_cast<const float4*>(part + 3 * PART_STRIDE + i);
    float4 r;
    r.x = (a.x + b.x) + (c.x + d.x);
    r.y = (a.y + b.y) + (c.y + d.y);
    r.z = (a.z + b.z) + (c.z + d.z);
    r.w = (a.w + b.w) + (c.w + d.w);
    *reinterpret_cast<float4*>(low + i) = r;
}

// ---------------------------------------------------------------------------
// Phase 2 (beff-in-registers streaming): thread owns h0, h0+1 with the gated
// beff[2][32] in 64 VGPRs; marches 64 s-rows. Per row: 8 wave-uniform float4
// loads of the low-row (L2 broadcast), float2 base read, 64 FMA, float2 store.
// No LDS, no barriers. grid (7, 32, 8) = 1792 blocks x 256 threads.
// ---------------------------------------------------------------------------
__global__ __launch_bounds__(256) void lora_apply_kernel(
    const float* __restrict__ base, const float* __restrict__ lora_B,
    const float* __restrict__ topk_w, const int* __restrict__ topk_idx,
    const float* __restrict__ low, float* __restrict__ out)
{
    const int tid = threadIdx.x;
    const int b   = blockIdx.z;
    const int s0  = blockIdx.y * 64;
    const int h0  = blockIdx.x * 512 + tid * 2;

    const int e0 = __builtin_amdgcn_readfirstlane(topk_idx[b * KK + 0]);
    const int e1 = __builtin_amdgcn_readfirstlane(topk_idx[b * KK + 1]);
    const float w0 = topk_w[b * KK + 0] * SCALE;
    const float w1 = topk_w[b * KK + 1] * SCALE;

    // beff[j][kr] = w_k * SCALE * lora_B[e_k][h0+j][r]
    float bf0[KR], bf1[KR];
    #pragma unroll
    for (int r4 = 0; r4 < 4; ++r4) {
        const float4 v00 = *reinterpret_cast<const float4*>(
            lora_B + ((size_t)e0 * HH + h0) * RR + r4 * 4);
        const float4 v01 = *reinterpret_cast<const float4*>(
            lora_B + ((size_t)e0 * HH + h0 + 1) * RR + r4 * 4);
        const float4 v10 = *reinterpret_cast<const float4*>(
            lora_B + ((size_t)e1 * HH + h0) * RR + r4 * 4);
        const float4 v11 = *reinterpret_cast<const float4*>(
            lora_B + ((size_t)e1 * HH + h0 + 1) * RR + r4 * 4);
        bf0[r4 * 4 + 0] = v00.x * w0;  bf0[r4 * 4 + 1] = v00.y * w0;
        bf0[r4 * 4 + 2] = v00.z * w0;  bf0[r4 * 4 + 3] = v00.w * w0;
        bf1[r4 * 4 + 0] = v01.x * w0;  bf1[r4 * 4 + 1] = v01.y * w0;
        bf1[r4 * 4 + 2] = v01.z * w0;  bf1[r4 * 4 + 3] = v01.w * w0;
        bf0[RR + r4 * 4 + 0] = v10.x * w1;  bf0[RR + r4 * 4 + 1] = v10.y * w1;
        bf0[RR + r4 * 4 + 2] = v10.z * w1;  bf0[RR + r4 * 4 + 3] = v10.w * w1;
        bf1[RR + r4 * 4 + 0] = v11.x * w1;  bf1[RR + r4 * 4 + 1] = v11.y * w1;
        bf1[RR + r4 * 4 + 2] = v11.z * w1;  bf1[RR + r4 * 4 + 3] = v11.w * w1;
    }

    const float* lp    = low  + ((size_t)b * SS + s0) * KR;
    const float* basep = base + ((size_t)(b * SS + s0)) * HH + h0;
    float*       outp  = out  + ((size_t)(b * SS + s0)) * HH + h0;

    for (int s = 0; s < 64; ++s) {
        float lv[KR];
        #pragma unroll
        for (int i = 0; i < 8; ++i) {
            const float4 t = *reinterpret_cast<const float4*>(lp + s * KR + i * 4);
            lv[i * 4 + 0] = t.x; lv[i * 4 + 1] = t.y;
            lv[i * 4 + 2] = t.z; lv[i * 4 + 3] = t.w;
        }
        const float2 bb = *reinterpret_cast<const float2*>(basep + (size_t)s * HH);
        float a0 = bb.x, a1 = bb.y, c0 = 0.0f, c1 = 0.0f;   // split dep chains
        #pragma unroll
        for (int kr = 0; kr < KR; kr += 2) {
            a0 = fmaf(lv[kr],     bf0[kr],     a0);
            a1 = fmaf(lv[kr],     bf1[kr],     a1);
            c0 = fmaf(lv[kr + 1], bf0[kr + 1], c0);
            c1 = fmaf(lv[kr + 1], bf1[kr + 1], c1);
        }
        float2 o;
        o.x = a0 + c0;
        o.y = a1 + c1;
        *reinterpret_cast<float2*>(outp + (size_t)s * HH) = o;
    }
}

// ---------------------------------------------------------------------------
extern "C" void kernel_launch(void* const* d_in, const int* in_sizes, int n_in,
                              void* d_out, int out_size, void* d_ws, size_t ws_size,
                              hipStream_t stream)
{
    const float* x      = (const float*)d_in[0];
    const float* basep  = (const float*)d_in[1];
    const float* lora_A = (const float*)d_in[2];
    const float* lora_B = (const float*)d_in[3];
    const float* topk_w = (const float*)d_in[4];
    const int*   tk_idx = (const int*)d_in[5];
    float*       out    = (float*)d_out;
    float*       low    = (float*)d_ws;     // 2 MB, read by p2 while out is written

    float* a2t  = out;                      // scratch in d_out (see layout note)
    float* part = out + A2T_FLOATS;

    prep_kernel<<<dim3(BB * HH / 256), 256, 0, stream>>>(lora_A, tk_idx, a2t);
    lora_low_kernel<<<dim3(4, SS / 64, BB), 256, 0, stream>>>(x, a2t, part);
    reduce_kernel<<<dim3((PART_STRIDE / 4) / 256), 256, 0, stream>>>(part, low);
    lora_apply_kernel<<<dim3(HH / 512, SS / 64, BB), 256, 0, stream>>>(
        basep, lora_B, topk_w, tk_idx, low, out);
}

// Round 2
// 548.796 us; speedup vs baseline: 1.4244x; 1.3659x over previous
//
#include <hip/hip_runtime.h>

#define BB 8
#define SS 2048
#define HH 3584
#define RR 16
#define KK 2
#define KR 32
#define SCALE 2.0f     // lora_alpha / lora_r

// ===========================================================================
// Phase 1: low[b][s][kr] = sum_h x[b][s][h] * A[e_k][r][h]   (no gate here)
// block = 512 threads (8 waves); tile = 32 s-rows x full-H sweep.
// Per 64-h chunk: x staged coalesced -> xt[32][68], A staged transposed ->
// at[64][36]; wave w computes h-slice [w*8,w*8+8); lane (sq=l&15,krg=l>>4)
// owns rows {sq,sq+16} x kr [krg*8,+8) -> acc[2][8] in regs.
// Double-buffered, reg-staged, ONE barrier per chunk. Cross-wave tree reduce
// once at the end (red aliases the dead buffer-0 region). No atomics.
// grid (SS/32=64, BB=8) = 512 blocks -> 2 blocks/CU, 16 waves/CU.
// ===========================================================================
#define P1_CH    64
#define XT_STR   68                     // 272 B row stride (16B-aligned, 2-way reads)
#define AT_STR   36                     // 144 B row stride (16B-aligned, conflict-free reads)
#define XT_FLTS  (32 * XT_STR)          // 2176
#define AT_FLTS  (P1_CH * AT_STR)       // 2304
#define BUF_FLTS (XT_FLTS + AT_FLTS)    // 4480 floats = 17920 B / buffer
#define NCHUNK   (HH / P1_CH)           // 56

__global__ __launch_bounds__(512) void lora_low_kernel(
    const float* __restrict__ x, const float* __restrict__ lora_A,
    const int* __restrict__ topk_idx, float* __restrict__ low)
{
    __shared__ float lds[2 * BUF_FLTS];     // 35840 B -> 4 blocks/CU capacity

    const int t   = threadIdx.x;
    const int b   = blockIdx.y;
    const int s0  = blockIdx.x * 32;
    const int w   = t >> 6;                 // wave 0..7 -> h sub-slice
    const int l   = t & 63;
    const int sq  = l & 15;                 // rows {sq, sq+16}
    const int krg = l >> 4;                 // kr group 0..3 -> kr [krg*8, +8)

    const int e0 = topk_idx[b * KK + 0];
    const int e1 = topk_idx[b * KK + 1];

    // staging mapping: thread loads 1 float4 of x and 1 float4 of A per chunk
    const int xrow = t >> 4;                // 0..31
    const int xc4  = t & 15;                // 0..15 -> 16 lanes x 64 B per row
    const int akr  = t >> 4;                // 0..31 (kr row of A)
    const int ac4  = t & 15;
    const int ae   = (akr < 16) ? e0 : e1;
    const int arow = akr & 15;

    const float* xsrc = x + ((size_t)(b * SS + s0 + xrow)) * HH + xc4 * 4;
    const float* asrc = lora_A + ((size_t)(ae * RR + arow)) * HH + ac4 * 4;

    float4 xr = *(const float4*)(xsrc);     // prefetch chunk 0
    float4 ar = *(const float4*)(asrc);

    float acc[2][8];
    #pragma unroll
    for (int i = 0; i < 2; ++i)
        #pragma unroll
        for (int j = 0; j < 8; ++j) acc[i][j] = 0.0f;

    for (int c = 0; c < NCHUNK; ++c) {
        float* xt = lds + (c & 1) * BUF_FLTS;
        float* at = xt + XT_FLTS;

        // ---- write staged chunk c to LDS (disjoint from buffer being read) ----
        *(float4*)&xt[xrow * XT_STR + xc4 * 4] = xr;
        at[(ac4 * 4 + 0) * AT_STR + akr] = ar.x;
        at[(ac4 * 4 + 1) * AT_STR + akr] = ar.y;
        at[(ac4 * 4 + 2) * AT_STR + akr] = ar.z;
        at[(ac4 * 4 + 3) * AT_STR + akr] = ar.w;
        __syncthreads();

        // ---- issue next chunk's global loads (in flight during compute) ----
        if (c + 1 < NCHUNK) {
            xr = *(const float4*)(xsrc + (c + 1) * P1_CH);
            ar = *(const float4*)(asrc + (c + 1) * P1_CH);
        }

        // ---- compute this wave's 8-h slice ----
        #pragma unroll
        for (int hh = 0; hh < 8; hh += 4) {
            const int hb = w * 8 + hh;
            const float4 x0 = *(const float4*)&xt[sq * XT_STR + hb];
            const float4 x1 = *(const float4*)&xt[(sq + 16) * XT_STR + hb];
            const float xs0[4] = {x0.x, x0.y, x0.z, x0.w};
            const float xs1[4] = {x1.x, x1.y, x1.z, x1.w};
            #pragma unroll
            for (int j = 0; j < 4; ++j) {
                const float4 a0 = *(const float4*)&at[(hb + j) * AT_STR + krg * 8];
                const float4 a1 = *(const float4*)&at[(hb + j) * AT_STR + krg * 8 + 4];
                acc[0][0] = fmaf(xs0[j], a0.x, acc[0][0]);
                acc[0][1] = fmaf(xs0[j], a0.y, acc[0][1]);
                acc[0][2] = fmaf(xs0[j], a0.z, acc[0][2]);
                acc[0][3] = fmaf(xs0[j], a0.w, acc[0][3]);
                acc[0][4] = fmaf(xs0[j], a1.x, acc[0][4]);
                acc[0][5] = fmaf(xs0[j], a1.y, acc[0][5]);
                acc[0][6] = fmaf(xs0[j], a1.z, acc[0][6]);
                acc[0][7] = fmaf(xs0[j], a1.w, acc[0][7]);
                acc[1][0] = fmaf(xs1[j], a0.x, acc[1][0]);
                acc[1][1] = fmaf(xs1[j], a0.y, acc[1][1]);
                acc[1][2] = fmaf(xs1[j], a0.z, acc[1][2]);
                acc[1][3] = fmaf(xs1[j], a0.w, acc[1][3]);
                acc[1][4] = fmaf(xs1[j], a1.x, acc[1][4]);
                acc[1][5] = fmaf(xs1[j], a1.y, acc[1][5]);
                acc[1][6] = fmaf(xs1[j], a1.z, acc[1][6]);
                acc[1][7] = fmaf(xs1[j], a1.w, acc[1][7]);
            }
        }
        // next iter's writes go to the other buffer; its barrier protects them
    }

    // ---- cross-wave tree reduce: 8 partials -> wave 0 ----
    // red aliases buffer 0 (dead: last compute used buffer 1, c=55).
    float* red = lds;                       // 4 groups x 64 lanes x 16 floats = 16 KB

    #define RED_ST(g) {                                                        \
        float* rp = red + ((g) * 64 + l) * 16;                                 \
        *(float4*)(rp + 0)  = make_float4(acc[0][0], acc[0][1], acc[0][2], acc[0][3]); \
        *(float4*)(rp + 4)  = make_float4(acc[0][4], acc[0][5], acc[0][6], acc[0][7]); \
        *(float4*)(rp + 8)  = make_float4(acc[1][0], acc[1][1], acc[1][2], acc[1][3]); \
        *(float4*)(rp + 12) = make_float4(acc[1][4], acc[1][5], acc[1][6], acc[1][7]); }
    #define RED_ADD(g) {                                                       \
        const float* rp = red + ((g) * 64 + l) * 16;                           \
        _Pragma("unroll") for (int j = 0; j < 8; ++j) acc[0][j] += rp[j];      \
        _Pragma("unroll") for (int j = 0; j < 8; ++j) acc[1][j] += rp[8 + j]; }

    if (w >= 4) RED_ST(w - 4);
    __syncthreads();
    if (w < 4) RED_ADD(w);
    __syncthreads();
    if (w == 2 || w == 3) RED_ST(w - 2);
    __syncthreads();
    if (w < 2) RED_ADD(w);
    __syncthreads();
    if (w == 1) RED_ST(0);
    __syncthreads();
    if (w == 0) {
        RED_ADD(0);
        float* lp = low + ((size_t)(b * SS + s0 + sq)) * KR + krg * 8;
        *(float4*)(lp)     = make_float4(acc[0][0], acc[0][1], acc[0][2], acc[0][3]);
        *(float4*)(lp + 4) = make_float4(acc[0][4], acc[0][5], acc[0][6], acc[0][7]);
        float* lp2 = lp + (size_t)16 * KR;
        *(float4*)(lp2)     = make_float4(acc[1][0], acc[1][1], acc[1][2], acc[1][3]);
        *(float4*)(lp2 + 4) = make_float4(acc[1][4], acc[1][5], acc[1][6], acc[1][7]);
    }
}

// ===========================================================================
// Phase 2: out[b][s][h] = base + sum_kr low[b][s][kr] * bt[kr][h]
//          bt[k*16+r][h] = w_k * SCALE * lora_B[e_k][h][r]
// block = 256 threads; tile 32 s x 128 h, staged once (no loop).
// bt[kr][h] contiguous-in-h -> conflict-free b128 reads; base loads issued
// before staging so HBM latency hides under it. Streaming, no inner barriers.
// grid (28, 64, 8) = 14336 blocks; LDS 21.5 KB -> ~28 waves/CU.
// ===========================================================================
#define P2_SR   32
#define P2_HC   128
#define BT_STR  132                       // 528 B (16B-aligned)
#define LT_STR  36

__global__ __launch_bounds__(256) void lora_apply_kernel(
    const float* __restrict__ base, const float* __restrict__ lora_B,
    const float* __restrict__ topk_w, const int* __restrict__ topk_idx,
    const float* __restrict__ low, float* __restrict__ out)
{
    __shared__ float bt[KR * BT_STR];     // 16896 B
    __shared__ float lt[P2_SR * LT_STR];  // 4608 B

    const int t  = threadIdx.x;
    const int b  = blockIdx.z;
    const int s0 = blockIdx.y * P2_SR;
    const int h0 = blockIdx.x * P2_HC;
    const int sy = t >> 5;                // 0..7  -> rows sy + 8*i
    const int hx = t & 31;                // 0..31 -> cols hx*4..+3

    // ---- issue base loads first: latency hides under staging ----
    const size_t brow = (size_t)(b * SS + s0);
    float4 acc[4];
    #pragma unroll
    for (int i = 0; i < 4; ++i)
        acc[i] = *(const float4*)(base + (brow + sy + 8 * i) * HH + h0 + hx * 4);

    // ---- stage low tile: 32 rows x 32 kr ----
    {
        const int row = t >> 3, q = t & 7;
        const float4 v = *(const float4*)(low + (brow + row) * KR + q * 4);
        *(float4*)&lt[row * LT_STR + q * 4] = v;
    }

    // ---- stage gated bt[kr][h] ----
    const int e0 = topk_idx[b * KK + 0];
    const int e1 = topk_idx[b * KK + 1];
    const float w0 = topk_w[b * KK + 0] * SCALE;
    const float w1 = topk_w[b * KK + 1] * SCALE;
    #pragma unroll
    for (int f = 0; f < 4; ++f) {
        const int idx = t + f * 256;      // 0..1023
        const int h   = idx >> 3;         // 0..127
        const int u   = idx & 7;
        const int k   = u >> 2;
        const int r4  = u & 3;
        const int   e  = k ? e1 : e0;
        const float wk = k ? w1 : w0;
        const float4 v = *(const float4*)(
            lora_B + ((size_t)e * HH + h0 + h) * RR + r4 * 4);
        bt[(k * 16 + r4 * 4 + 0) * BT_STR + h] = v.x * wk;
        bt[(k * 16 + r4 * 4 + 1) * BT_STR + h] = v.y * wk;
        bt[(k * 16 + r4 * 4 + 2) * BT_STR + h] = v.z * wk;
        bt[(k * 16 + r4 * 4 + 3) * BT_STR + h] = v.w * wk;
    }
    __syncthreads();

    // ---- rank-32 update: 8 kr-quads, b128 LDS reads throughout ----
    #pragma unroll
    for (int kq = 0; kq < 8; ++kq) {
        float4 bv[4];
        #pragma unroll
        for (int j = 0; j < 4; ++j)
            bv[j] = *(const float4*)&bt[(kq * 4 + j) * BT_STR + hx * 4];
        #pragma unroll
        for (int i = 0; i < 4; ++i) {
            const float4 l4 = *(const float4*)&lt[(sy + 8 * i) * LT_STR + kq * 4];
            acc[i].x = fmaf(l4.x, bv[0].x, acc[i].x);
            acc[i].y = fmaf(l4.x, bv[0].y, acc[i].y);
            acc[i].z = fmaf(l4.x, bv[0].z, acc[i].z);
            acc[i].w = fmaf(l4.x, bv[0].w, acc[i].w);
            acc[i].x = fmaf(l4.y, bv[1].x, acc[i].x);
            acc[i].y = fmaf(l4.y, bv[1].y, acc[i].y);
            acc[i].z = fmaf(l4.y, bv[1].z, acc[i].z);
            acc[i].w = fmaf(l4.y, bv[1].w, acc[i].w);
            acc[i].x = fmaf(l4.z, bv[2].x, acc[i].x);
            acc[i].y = fmaf(l4.z, bv[2].y, acc[i].y);
            acc[i].z = fmaf(l4.z, bv[2].z, acc[i].z);
            acc[i].w = fmaf(l4.z, bv[2].w, acc[i].w);
            acc[i].x = fmaf(l4.w, bv[3].x, acc[i].x);
            acc[i].y = fmaf(l4.w, bv[3].y, acc[i].y);
            acc[i].z = fmaf(l4.w, bv[3].z, acc[i].z);
            acc[i].w = fmaf(l4.w, bv[3].w, acc[i].w);
        }
    }

    // ---- store ----
    #pragma unroll
    for (int i = 0; i < 4; ++i)
        *(float4*)(out + (brow + sy + 8 * i) * HH + h0 + hx * 4) = acc[i];
}

// ---------------------------------------------------------------------------
extern "C" void kernel_launch(void* const* d_in, const int* in_sizes, int n_in,
                              void* d_out, int out_size, void* d_ws, size_t ws_size,
                              hipStream_t stream)
{
    const float* x      = (const float*)d_in[0];
    const float* basep  = (const float*)d_in[1];
    const float* lora_A = (const float*)d_in[2];
    const float* lora_B = (const float*)d_in[3];
    const float* topk_w = (const float*)d_in[4];
    const int*   tk_idx = (const int*)d_in[5];
    float*       out    = (float*)d_out;
    float*       low    = (float*)d_ws;   // 2 MB, fully written by p1 (no memset)

    lora_low_kernel<<<dim3(SS / 32, BB), 512, 0, stream>>>(x, lora_A, tk_idx, low);
    lora_apply_kernel<<<dim3(HH / P2_HC, SS / P2_SR, BB), 256, 0, stream>>>(
        basep, lora_B, topk_w, tk_idx, low, out);
}